// Round 10
// baseline (127.533 us; speedup 1.0000x reference)
//
#include <hip/hip_runtime.h>
#include <stdint.h>

typedef __attribute__((ext_vector_type(8))) short short8;
typedef __attribute__((ext_vector_type(4))) float f32x4;
typedef __attribute__((ext_vector_type(4))) uint32_t u32x4;

#if __has_builtin(__builtin_amdgcn_exp2f)
#define EXP2(x) __builtin_amdgcn_exp2f(x)
#else
#define EXP2(x) exp2f(x)
#endif

// round-nearest-ties-away bf16: statistically unbiased, 2 VALU ops
__device__ __forceinline__ short f2bf(float f){
  uint32_t u = __builtin_bit_cast(uint32_t, f);
  return (short)((u + 0x8000u) >> 16);
}
// pack two rounded bf16 (lo in low half): 2 adds + 1 v_perm
__device__ __forceinline__ uint32_t pk2(float lo, float hi){
  uint32_t a = __builtin_bit_cast(uint32_t, lo) + 0x8000u;
  uint32_t b = __builtin_bit_cast(uint32_t, hi) + 0x8000u;
#if __has_builtin(__builtin_amdgcn_perm)
  return __builtin_amdgcn_perm(b, a, 0x07060302u);   // [b3 b2 a3 a2]
#else
  return (b & 0xFFFF0000u) | (a >> 16);
#endif
}
__device__ __forceinline__ void gload16(const void* g, void* l){
  __builtin_amdgcn_global_load_lds((const __attribute__((address_space(1))) void*)g,
                                   (__attribute__((address_space(3))) void*)l, 16, 0, 0);
}

// ---------------- fp32 -> bf16 conversion of q,k,v,Wq,Wk,Wv,Wo ----------------
__global__ __launch_bounds__(512) void cvt_all(
    const float* __restrict__ q, const float* __restrict__ k, const float* __restrict__ v,
    const float* __restrict__ wq, const float* __restrict__ wk, const float* __restrict__ wv,
    const float* __restrict__ wo, short* __restrict__ dst){
  const size_t SQ = 4096ull*1024ull, NW = 1024ull*1024ull;
  size_t e = (size_t)(blockIdx.x*512u + threadIdx.x)*8ull;
  const float* src; size_t rel;
  if (e < 3*SQ){ size_t which = e / SQ; src = which==0?q:(which==1?k:v); rel = e - which*SQ; }
  else { size_t e2 = e - 3*SQ; size_t which = e2 / NW;
         src = which==0?wq:(which==1?wk:(which==2?wv:wo)); rel = e2 - which*NW; }
  float4 a = *(const float4*)(src + rel);
  float4 b = *(const float4*)(src + rel + 4);
  u32x4 r = { pk2(a.x,a.y), pk2(a.z,a.w), pk2(b.x,b.y), pk2(b.z,b.w) };
  *(u32x4*)(dst + e) = r;
}

// ---------------- NT GEMM core: 128x64 tile, BK=64, 512 thr, XOR-swizzled LDS ----------------
template<int MODE>
__device__ __forceinline__ void gemm_body(const short* __restrict__ A, const short* __restrict__ Bw,
    const float* __restrict__ bias, void* __restrict__ Cout, float scale, int m0, int n0){
  const int K = 1024;
  __shared__ short Al[128*64];
  __shared__ short Bl[64*64];
  int tid = threadIdx.x;
  int w = tid >> 6, lane = tid & 63, lr = lane & 15, lg = lane >> 4;
  int wr = w >> 1, wc = w & 1;
  f32x4 acc[2][2] = {};
  int row0 = tid >> 3;                       // 0..63
  int qc0  = (tid & 7) ^ (row0 & 7);
  const short* Ag = A  + (size_t)(m0 + row0)*K + qc0*8;
  const short* Bg = Bw + (size_t)(n0 + row0)*K + qc0*8;
  char* Alb = (char*)Al + tid*16;
  char* Blb = (char*)Bl + tid*16;
  int ra[2], rb[2];
#pragma unroll
  for (int mi=0; mi<2; ++mi){ int r = wr*32 + mi*16 + lr; ra[mi] = r; }
#pragma unroll
  for (int ni=0; ni<2; ++ni){ int r = wc*32 + ni*16 + lr; rb[ni] = r; }
  for (int k0 = 0; k0 < K; k0 += 64){
    gload16(Ag + k0,                Alb);
    gload16(Ag + k0 + 64*(size_t)K, Alb + 8192);
    gload16(Bg + k0,                Blb);
    __syncthreads();
#pragma unroll
    for (int kk=0; kk<2; ++kk){
      short8 av[2], bv[2];
#pragma unroll
      for (int mi=0; mi<2; ++mi)
        av[mi] = *(const short8*)((char*)Al + ra[mi]*128 + (((kk*4 + lg) ^ (ra[mi] & 7)) << 4));
#pragma unroll
      for (int ni=0; ni<2; ++ni)
        bv[ni] = *(const short8*)((char*)Bl + rb[ni]*128 + (((kk*4 + lg) ^ (rb[ni] & 7)) << 4));
#pragma unroll
      for (int mi=0; mi<2; ++mi)
#pragma unroll
        for (int ni=0; ni<2; ++ni)
          acc[mi][ni] = __builtin_amdgcn_mfma_f32_16x16x32_bf16(av[mi], bv[ni], acc[mi][ni], 0, 0, 0);
    }
    __syncthreads();
  }
#pragma unroll
  for (int ni=0; ni<2; ++ni){
    int col = n0 + wc*32 + ni*16 + lr;
    float bb = bias[col];
#pragma unroll
    for (int mi=0; mi<2; ++mi){
#pragma unroll
      for (int i2=0; i2<4; ++i2){
        int row = m0 + wr*32 + mi*16 + lg*4 + i2;
        float val = (acc[mi][ni][i2] + bb) * scale;
        if (MODE == 0){
          int b = row >> 11, s = row & 2047, h = col >> 6, d = col & 63;
          ((short*)Cout)[(((size_t)(b*16 + h))*2048 + s)*64 + d] = f2bf(val);
        } else {
          ((float*)Cout)[(size_t)row*1024 + col] = val;
        }
      }
    }
  }
}

__global__ __launch_bounds__(512) void gemm_qkv(
    const short* __restrict__ qb, const short* __restrict__ kb, const short* __restrict__ vb,
    const short* __restrict__ Wqb, const short* __restrict__ Wkb, const short* __restrict__ Wvb,
    const float* __restrict__ bq, const float* __restrict__ bk, const float* __restrict__ bv,
    short* __restrict__ Qh, short* __restrict__ Kh, short* __restrict__ Vh, float qscale){
  int f = (blockIdx.z*32 + blockIdx.y)*16 + blockIdx.x;   // 0..1535
  int L = (f & 7)*192 + (f >> 3);
  int z = L >> 9, r = L & 511;
  int m0 = (r >> 4)*128, n0 = (r & 15)*64;
  const short* A  = z==0 ? qb  : (z==1 ? kb  : vb);
  const short* Bw = z==0 ? Wqb : (z==1 ? Wkb : Wvb);
  const float* bi = z==0 ? bq  : (z==1 ? bk  : bv);
  short* C        = z==0 ? Qh  : (z==1 ? Kh  : Vh);
  float s = z==0 ? qscale : 1.0f;
  gemm_body<0>(A, Bw, bi, (void*)C, s, m0, n0);
}

__global__ __launch_bounds__(512) void gemm_out(const short* __restrict__ A, const short* __restrict__ Bw,
    const float* __restrict__ bias, float* __restrict__ Cout){
  int f = blockIdx.y*gridDim.x + blockIdx.x;
  int L = (f & 7)*64 + (f >> 3);
  int m0 = (L >> 4)*128, n0 = (L & 15)*64;
  gemm_body<1>(A, Bw, bias, (void*)Cout, 1.0f, m0, n0);
}

// ---------------- flash attention: 4 waves x 32 q-rows, register P, counted-vmcnt ----------------
// Swapped QK^T with permuted K-rows (R6-verified): iteration nf covers K rows
// R = 32*(nf>>1) + 8*(lr>>2) + 4*(nf&1) + (lr&3); lane(lg) accumulates scores for
// k = 32c + 8*lg + 4*(nf&1) + i2 — exactly the PV A-fragment set (P never leaves regs).
// 32 q-rows/wave: each K/V ds_read_b128 now feeds 2 MFMAs -> LDS read traffic per unit work halves.
// Q pre-scaled by log2(e)/8 in the projection, so p = exp2(z) directly.
__global__ __launch_bounds__(256) void attn_fwd(const short* __restrict__ Qh, const short* __restrict__ Kh,
    const short* __restrict__ Vh, short* __restrict__ AO){
  const int S = 2048;
  int i = blockIdx.y*gridDim.x + blockIdx.x;   // 512 wgs
  int L = (i & 7)*64 + (i >> 3);
  int bh = L >> 4, qt = L & 15;
  __shared__ short Kl[3][4096];      // 3-buffer K; read-slot swizzle, source-side
  __shared__ short Vt[2][64*72];     // dbuf V^T[d][k], col swizzle k ^ (d&56)
  int tid = threadIdx.x, w = tid >> 6, lane = tid & 63, lr = lane & 15, lg = lane >> 4;
  const short* Qb = Qh + (size_t)bh*S*64;
  const short* Kb = Kh + (size_t)bh*S*64;
  const short* Vb = Vh + (size_t)bh*S*64;
  int q0 = qt*128 + w*32;
  short8 aq[2][2];
#pragma unroll
  for (int m=0; m<2; ++m)
#pragma unroll
    for (int h=0; h<2; ++h)
      aq[m][h] = *(const short8*)&Qb[(size_t)(q0 + m*16 + lr)*64 + h*32 + lg*8];
  f32x4 o[2][4] = {};
  float lsum[2] = {0.f, 0.f};
  // K staging: 2 gload16/thread (rows 0-31, 32-63); LDS dest linear, source pre-swizzled
  int koff = tid*16;
  int kr = tid >> 3, kc = tid & 7;
  int ksw = (kr & 3) | (((kr >> 3) & 1) << 2);
  int ksrc = kr*64 + ((kc ^ ksw) << 3);        // rows 0-31; +2048 elems covers rows 32-63 (same swizzle)
  // K read addressing
  int Rbase = 8*(lr >> 2) + (lr & 3);
  int sR = (lr & 3) | (((lr >> 2) & 1) << 2);
  int slot0 = (lg ^ sR) << 3, slot1 = ((lg + 4) ^ sR) << 3;
  // V staging: 2 short8 loads + 16 b16 writes/thread (rows vr, vr+32)
  int vr = tid >> 3;                 // k-row 0..31
  int d0 = (tid & 7)*8;
  int c0 = vr ^ d0, c1 = (vr + 32) ^ d0;
  // ---- prologue: K[0]->Kl[0], K[1]->Kl[1], V[0]->Vt[0] ----
  gload16(Kb + ksrc,               (char*)&Kl[0][0] + koff);
  gload16(Kb + ksrc + 2048,        (char*)&Kl[0][0] + koff + 4096);
  gload16(Kb + 4096 + ksrc,        (char*)&Kl[1][0] + koff);
  gload16(Kb + 4096 + ksrc + 2048, (char*)&Kl[1][0] + koff + 4096);
  {
    short8 v0 = *(const short8*)&Vb[(size_t)vr*64 + d0];
    short8 v1 = *(const short8*)&Vb[(size_t)(vr + 32)*64 + d0];
#pragma unroll
    for (int j=0; j<8; ++j){ Vt[0][(d0 + j)*72 + c0] = v0[j]; Vt[0][(d0 + j)*72 + c1] = v1[j]; }
  }
  asm volatile("s_waitcnt vmcnt(2) lgkmcnt(0)" ::: "memory");  // K[0] landed; K[1] pair in flight
  __builtin_amdgcn_sched_barrier(0);
  __builtin_amdgcn_s_barrier();

  for (int t = 0; t < 32; ++t){
    int buf = t % 3;
    short8 nv0, nv1;
    if (t + 1 < 32){
      nv0 = *(const short8*)&Vb[(size_t)((t + 1)*64 + vr)*64 + d0];
      nv1 = *(const short8*)&Vb[(size_t)((t + 1)*64 + vr + 32)*64 + d0];
    }
    if (t + 2 < 32){
      const short* Kt = Kb + (size_t)(t + 2)*4096;
      char* Kd = (char*)&Kl[(t + 2) % 3][0] + koff;
      gload16(Kt + ksrc,        Kd);
      gload16(Kt + ksrc + 2048, Kd + 4096);
    }
    // QK^T (swapped, permuted K-rows) + exp2; P accumulates into A-fragment registers
    const short* Kbuf = &Kl[buf][0];
    uint32_t Wp[2][2][2][2];   // [m][c][nf0][s]
    __builtin_amdgcn_s_setprio(1);
#pragma unroll
    for (int nf=0; nf<4; ++nf){
      int R = Rbase + (nf & 1)*4 + (nf >> 1)*32;
      short8 ak0 = *(const short8*)&Kbuf[R*64 + slot0];
      short8 ak1 = *(const short8*)&Kbuf[R*64 + slot1];
#pragma unroll
      for (int m=0; m<2; ++m){
        f32x4 z = {};
        z = __builtin_amdgcn_mfma_f32_16x16x32_bf16(ak0, aq[m][0], z, 0, 0, 0);
        z = __builtin_amdgcn_mfma_f32_16x16x32_bf16(ak1, aq[m][1], z, 0, 0, 0);
        float p0 = EXP2(z[0]), p1 = EXP2(z[1]);
        float p2 = EXP2(z[2]), p3 = EXP2(z[3]);
        lsum[m] += (p0 + p1) + (p2 + p3);
        Wp[m][nf >> 1][nf & 1][0] = pk2(p0, p1);
        Wp[m][nf >> 1][nf & 1][1] = pk2(p2, p3);
      }
    }
    __builtin_amdgcn_s_setprio(0);
    short8 pa[2][2];
#pragma unroll
    for (int m=0; m<2; ++m)
#pragma unroll
      for (int c=0; c<2; ++c){
        union { uint32_t u[4]; short8 s; } tt;
        tt.u[0] = Wp[m][c][0][0]; tt.u[1] = Wp[m][c][0][1];
        tt.u[2] = Wp[m][c][1][0]; tt.u[3] = Wp[m][c][1][1];
        pa[m][c] = tt.s;
      }
    // PV: O += P·V (each V fragment read feeds both m's)
    const short* Vbuf = &Vt[t & 1][0];
    __builtin_amdgcn_s_setprio(1);
#pragma unroll
    for (int df=0; df<4; ++df){
      int h = (df*2 + (lr >> 3)) & 7;
      int rowv = (df*16 + lr)*72;
      short8 vb0 = *(const short8*)&Vbuf[rowv + ((lg ^ h) << 3)];
      short8 vb1 = *(const short8*)&Vbuf[rowv + (((lg + 4) ^ h) << 3)];
#pragma unroll
      for (int m=0; m<2; ++m){
        o[m][df] = __builtin_amdgcn_mfma_f32_16x16x32_bf16(pa[m][0], vb0, o[m][df], 0, 0, 0);
        o[m][df] = __builtin_amdgcn_mfma_f32_16x16x32_bf16(pa[m][1], vb1, o[m][df], 0, 0, 0);
      }
    }
    __builtin_amdgcn_s_setprio(0);
    if (t + 1 < 32){
      short* Vn = &Vt[(t + 1) & 1][0];
#pragma unroll
      for (int j=0; j<8; ++j){ Vn[(d0 + j)*72 + c0] = nv0[j]; Vn[(d0 + j)*72 + c1] = nv1[j]; }
      // barrier with counted vmcnt: K[t+1] complete; K[t+2]'s 2 loads stay in flight
      if (t < 30) asm volatile("s_waitcnt vmcnt(2) lgkmcnt(0)" ::: "memory");
      else        asm volatile("s_waitcnt vmcnt(0) lgkmcnt(0)" ::: "memory");
      __builtin_amdgcn_sched_barrier(0);
      __builtin_amdgcn_s_barrier();
    }
  }
  // epilogue: reduce lsum across k-slice groups, normalize, write AO[b][s][h*64+d]
  lsum[0] += __shfl_xor(lsum[0], 16); lsum[0] += __shfl_xor(lsum[0], 32);
  lsum[1] += __shfl_xor(lsum[1], 16); lsum[1] += __shfl_xor(lsum[1], 32);
  int b = bh >> 4, hh = bh & 15;
#pragma unroll
  for (int m=0; m<2; ++m){
    float rinv[4];
#pragma unroll
    for (int i2=0; i2<4; ++i2) rinv[i2] = 1.0f / __shfl(lsum[m], (lg << 2) + i2);
#pragma unroll
    for (int df=0; df<4; ++df)
#pragma unroll
      for (int i2=0; i2<4; ++i2){
        int row = q0 + m*16 + lg*4 + i2;
        int col = df*16 + lr;
        AO[((size_t)(b*2048 + row))*1024 + hh*64 + col] = f2bf(o[m][df][i2] * rinv[i2]);
      }
  }
}

extern "C" void kernel_launch(void* const* d_in, const int* in_sizes, int n_in,
                              void* d_out, int out_size, void* d_ws, size_t ws_size,
                              hipStream_t stream){
  const float* q  = (const float*)d_in[0];
  const float* k  = (const float*)d_in[1];
  const float* v  = (const float*)d_in[2];
  const float* Wq = (const float*)d_in[3];
  const float* bq = (const float*)d_in[4];
  const float* Wk = (const float*)d_in[5];
  const float* bk = (const float*)d_in[6];
  const float* Wv = (const float*)d_in[7];
  const float* bv = (const float*)d_in[8];
  const float* Wo = (const float*)d_in[9];
  const float* bo = (const float*)d_in[10];

  const size_t SQ = 4096ull*1024ull, NW = 1024ull*1024ull;
  short* ws  = (short*)d_ws;
  short* qb  = ws;                    // bf16 q      [4096,1024]
  short* kb  = ws + SQ;
  short* vb  = ws + 2*SQ;
  short* Wqb = ws + 3*SQ;             // bf16 weights [1024,1024]
  short* Wkb = Wqb + NW;
  short* Wvb = Wkb + NW;
  short* Wob = Wvb + NW;
  short* Qh  = Wob + NW;              // [B,H,S,D] bf16 (Q pre-scaled by log2e/8)
  short* Kh  = Qh + SQ;
  short* Vh  = Kh + SQ;
  short* AO  = qb;                    // reuse q buffer for attention output

  const float Csc = 0.18033688011112042f;   // log2(e)/8

  cvt_all<<<4096, 512, 0, stream>>>(q, k, v, Wq, Wk, Wv, Wo, ws);
  gemm_qkv<<<dim3(16, 32, 3), 512, 0, stream>>>(qb, kb, vb, Wqb, Wkb, Wvb, bq, bk, bv, Qh, Kh, Vh, Csc);
  attn_fwd<<<dim3(16, 32), 256, 0, stream>>>(Qh, Kh, Vh, AO);
  gemm_out<<<dim3(16, 32), 512, 0, stream>>>(AO, Wob, bo, (float*)d_out);
}

// Round 11
// 120.484 us; speedup vs baseline: 1.0585x; 1.0585x over previous
//
#include <hip/hip_runtime.h>
#include <stdint.h>

typedef __attribute__((ext_vector_type(8))) short short8;
typedef __attribute__((ext_vector_type(4))) float f32x4;
typedef __attribute__((ext_vector_type(4))) uint32_t u32x4;

#if __has_builtin(__builtin_amdgcn_exp2f)
#define EXP2(x) __builtin_amdgcn_exp2f(x)
#else
#define EXP2(x) exp2f(x)
#endif

// round-nearest-ties-away bf16: statistically unbiased, 2 VALU ops
__device__ __forceinline__ short f2bf(float f){
  uint32_t u = __builtin_bit_cast(uint32_t, f);
  return (short)((u + 0x8000u) >> 16);
}
// pack two rounded bf16 (lo in low half): 2 adds + 1 v_perm
__device__ __forceinline__ uint32_t pk2(float lo, float hi){
  uint32_t a = __builtin_bit_cast(uint32_t, lo) + 0x8000u;
  uint32_t b = __builtin_bit_cast(uint32_t, hi) + 0x8000u;
#if __has_builtin(__builtin_amdgcn_perm)
  return __builtin_amdgcn_perm(b, a, 0x07060302u);   // [b3 b2 a3 a2]
#else
  return (b & 0xFFFF0000u) | (a >> 16);
#endif
}
__device__ __forceinline__ void gload16(const void* g, void* l){
  __builtin_amdgcn_global_load_lds((const __attribute__((address_space(1))) void*)g,
                                   (__attribute__((address_space(3))) void*)l, 16, 0, 0);
}

// ---------------- fp32 -> bf16 conversion of q,k,v,Wq,Wk,Wv,Wo ----------------
__global__ __launch_bounds__(512) void cvt_all(
    const float* __restrict__ q, const float* __restrict__ k, const float* __restrict__ v,
    const float* __restrict__ wq, const float* __restrict__ wk, const float* __restrict__ wv,
    const float* __restrict__ wo, short* __restrict__ dst){
  const size_t SQ = 4096ull*1024ull, NW = 1024ull*1024ull;
  size_t e = (size_t)(blockIdx.x*512u + threadIdx.x)*8ull;
  const float* src; size_t rel;
  if (e < 3*SQ){ size_t which = e / SQ; src = which==0?q:(which==1?k:v); rel = e - which*SQ; }
  else { size_t e2 = e - 3*SQ; size_t which = e2 / NW;
         src = which==0?wq:(which==1?wk:(which==2?wv:wo)); rel = e2 - which*NW; }
  float4 a = *(const float4*)(src + rel);
  float4 b = *(const float4*)(src + rel + 4);
  u32x4 r = { pk2(a.x,a.y), pk2(a.z,a.w), pk2(b.x,b.y), pk2(b.z,b.w) };
  *(u32x4*)(dst + e) = r;
}

// ---------------- NT GEMM core: 128x64 tile, BK=64, 512 thr, XOR-swizzled LDS ----------------
// MODE 0: bf16 head-scatter [b,h,s,d]. MODE 1: f32 linear. MODE 2: bf16 transposed head-scatter [b,h,d,s].
template<int MODE>
__device__ __forceinline__ void gemm_body(const short* __restrict__ A, const short* __restrict__ Bw,
    const float* __restrict__ bias, void* __restrict__ Cout, float scale, int m0, int n0){
  const int K = 1024;
  __shared__ short Al[128*64];
  __shared__ short Bl[64*64];
  int tid = threadIdx.x;
  int w = tid >> 6, lane = tid & 63, lr = lane & 15, lg = lane >> 4;
  int wr = w >> 1, wc = w & 1;
  f32x4 acc[2][2] = {};
  int row0 = tid >> 3;                       // 0..63
  int qc0  = (tid & 7) ^ (row0 & 7);
  const short* Ag = A  + (size_t)(m0 + row0)*K + qc0*8;
  const short* Bg = Bw + (size_t)(n0 + row0)*K + qc0*8;
  char* Alb = (char*)Al + tid*16;
  char* Blb = (char*)Bl + tid*16;
  int ra[2], rb[2];
#pragma unroll
  for (int mi=0; mi<2; ++mi){ int r = wr*32 + mi*16 + lr; ra[mi] = r; }
#pragma unroll
  for (int ni=0; ni<2; ++ni){ int r = wc*32 + ni*16 + lr; rb[ni] = r; }
  for (int k0 = 0; k0 < K; k0 += 64){
    gload16(Ag + k0,                Alb);
    gload16(Ag + k0 + 64*(size_t)K, Alb + 8192);
    gload16(Bg + k0,                Blb);
    __syncthreads();
#pragma unroll
    for (int kk=0; kk<2; ++kk){
      short8 av[2], bv[2];
#pragma unroll
      for (int mi=0; mi<2; ++mi)
        av[mi] = *(const short8*)((char*)Al + ra[mi]*128 + (((kk*4 + lg) ^ (ra[mi] & 7)) << 4));
#pragma unroll
      for (int ni=0; ni<2; ++ni)
        bv[ni] = *(const short8*)((char*)Bl + rb[ni]*128 + (((kk*4 + lg) ^ (rb[ni] & 7)) << 4));
#pragma unroll
      for (int mi=0; mi<2; ++mi)
#pragma unroll
        for (int ni=0; ni<2; ++ni)
          acc[mi][ni] = __builtin_amdgcn_mfma_f32_16x16x32_bf16(av[mi], bv[ni], acc[mi][ni], 0, 0, 0);
    }
    __syncthreads();
  }
#pragma unroll
  for (int ni=0; ni<2; ++ni){
    int col = n0 + wc*32 + ni*16 + lr;
    float bb = bias[col];
#pragma unroll
    for (int mi=0; mi<2; ++mi){
      if (MODE == 2){
        // transposed per-head scatter: 4 consecutive s for one d -> one 8B store
        int row = m0 + wr*32 + mi*16 + lg*4;
        int b = row >> 11, s = row & 2047, h = col >> 6, d = col & 63;
        uint2 val;
        val.x = pk2((acc[mi][ni][0] + bb)*scale, (acc[mi][ni][1] + bb)*scale);
        val.y = pk2((acc[mi][ni][2] + bb)*scale, (acc[mi][ni][3] + bb)*scale);
        *(uint2*)&((short*)Cout)[(((size_t)(b*16 + h))*64 + d)*2048 + s] = val;
      } else {
#pragma unroll
        for (int i2=0; i2<4; ++i2){
          int row = m0 + wr*32 + mi*16 + lg*4 + i2;
          float val = (acc[mi][ni][i2] + bb) * scale;
          if (MODE == 0){
            int b = row >> 11, s = row & 2047, h = col >> 6, d = col & 63;
            ((short*)Cout)[(((size_t)(b*16 + h))*2048 + s)*64 + d] = f2bf(val);
          } else {
            ((float*)Cout)[(size_t)row*1024 + col] = val;
          }
        }
      }
    }
  }
}

__global__ __launch_bounds__(512) void gemm_qkv(
    const short* __restrict__ qb, const short* __restrict__ kb, const short* __restrict__ vb,
    const short* __restrict__ Wqb, const short* __restrict__ Wkb, const short* __restrict__ Wvb,
    const float* __restrict__ bq, const float* __restrict__ bk, const float* __restrict__ bv,
    short* __restrict__ Qh, short* __restrict__ Kh, short* __restrict__ VhT, float qscale){
  int f = (blockIdx.z*32 + blockIdx.y)*16 + blockIdx.x;   // 0..1535
  int L = (f & 7)*192 + (f >> 3);
  int z = L >> 9, r = L & 511;
  int m0 = (r >> 4)*128, n0 = (r & 15)*64;
  const short* A  = z==0 ? qb  : (z==1 ? kb  : vb);
  const short* Bw = z==0 ? Wqb : (z==1 ? Wkb : Wvb);
  const float* bi = z==0 ? bq  : (z==1 ? bk  : bv);
  short* C        = z==0 ? Qh  : (z==1 ? Kh  : VhT);
  if (z == 2) gemm_body<2>(A, Bw, bi, (void*)C, 1.0f, m0, n0);
  else        gemm_body<0>(A, Bw, bi, (void*)C, z==0 ? qscale : 1.0f, m0, n0);
}

__global__ __launch_bounds__(512) void gemm_out(const short* __restrict__ A, const short* __restrict__ Bw,
    const float* __restrict__ bias, float* __restrict__ Cout){
  int f = blockIdx.y*gridDim.x + blockIdx.x;
  int L = (f & 7)*64 + (f >> 3);
  int m0 = (L >> 4)*128, n0 = (L & 15)*64;
  gemm_body<1>(A, Bw, bias, (void*)Cout, 1.0f, m0, n0);
}

// ---------------- flash attention: 8 waves x 16 q-rows, register P, K+V via gload16 ----------------
// Swapped QK^T with permuted K-rows (R6-verified): iteration nf covers K rows
// R = 32*(nf>>1) + 8*(lr>>2) + 4*(nf&1) + (lr&3); lane(lg) accumulates scores for
// k = 32c + 8*lg + 4*(nf&1) + i2 — exactly the PV A-fragment set (P never leaves regs).
// V pre-transposed by gemm_qkv (VhT[b,h,d,s]) -> staged like K (1 gload16, source XOR by d&7),
// PV B-frag = ds_read_b128 row (df*16+lr), chunk (4c+lg)^(lr&7). No transpose writes.
// Q pre-scaled by log2(e)/8 in the projection, so p = exp2(z) directly.
__global__ __launch_bounds__(512) void attn_fwd(const short* __restrict__ Qh, const short* __restrict__ Kh,
    const short* __restrict__ VhT, short* __restrict__ AO){
  const int S = 2048;
  int i = blockIdx.y*gridDim.x + blockIdx.x;   // 512 wgs
  int L = (i & 7)*64 + (i >> 3);
  int bh = L >> 4, qt = L & 15;
  __shared__ short Kl[3][4096];      // 3-buffer K; read-slot swizzle, source-side
  __shared__ short Vl[3][4096];      // 3-buffer V^T[d][k-chunk ^ (d&7)]
  int tid = threadIdx.x, w = tid >> 6, lane = tid & 63, lr = lane & 15, lg = lane >> 4;
  const short* Qb = Qh  + (size_t)bh*S*64;
  const short* Kb = Kh  + (size_t)bh*S*64;
  const short* Vb = VhT + (size_t)bh*64*2048;   // 64 d-rows of length S
  int q0 = qt*128 + w*16;
  short8 aq[2];
#pragma unroll
  for (int h=0; h<2; ++h)
    aq[h] = *(const short8*)&Qb[(size_t)(q0 + lr)*64 + h*32 + lg*8];
  f32x4 o[4] = {};
  float lsum = 0.f;
  // K staging: 1 gload16/thread; LDS dest linear, source pre-swizzled
  int koff = tid*16;
  int kr = tid >> 3, kc = tid & 7;
  int ksw = (kr & 3) | (((kr >> 3) & 1) << 2);
  int ksrc = kr*64 + ((kc ^ ksw) << 3);
  // V staging: 1 gload16/thread; row d = tid>>3 (stride 2048), chunk XOR by d&7
  int vsrc = kr*2048 + ((kc ^ (kr & 7)) << 3);
  // K read addressing
  int Rbase = 8*(lr >> 2) + (lr & 3);
  int sR = (lr & 3) | (((lr >> 2) & 1) << 2);
  int slot0 = (lg ^ sR) << 3, slot1 = ((lg + 4) ^ sR) << 3;
  // V read addressing: chunk xor term
  int vx = lr & 7;
  // ---- prologue: K/V tiles 0 and 1 ----
  gload16(Kb + ksrc,        (char*)&Kl[0][0] + koff);
  gload16(Vb + vsrc,        (char*)&Vl[0][0] + koff);
  gload16(Kb + 4096 + ksrc, (char*)&Kl[1][0] + koff);
  gload16(Vb + vsrc + 64,   (char*)&Vl[1][0] + koff);
  asm volatile("s_waitcnt vmcnt(2) lgkmcnt(0)" ::: "memory");  // tile 0 landed; tile 1 in flight
  __builtin_amdgcn_sched_barrier(0);
  __builtin_amdgcn_s_barrier();

  for (int t = 0; t < 32; ++t){
    int buf = t % 3;
    if (t + 2 < 32){
      int nb = (t + 2) % 3;
      gload16(Kb + (size_t)(t + 2)*4096 + ksrc, (char*)&Kl[nb][0] + koff);
      gload16(Vb + vsrc + (t + 2)*64,           (char*)&Vl[nb][0] + koff);
    }
    // QK^T (swapped, permuted K-rows) + exp2; P accumulates into A-fragment registers
    const short* Kbuf = &Kl[buf][0];
    uint32_t Wp[2][2][2];   // [c][nf0][s]
    __builtin_amdgcn_s_setprio(1);
#pragma unroll
    for (int nf=0; nf<4; ++nf){
      int R = Rbase + (nf & 1)*4 + (nf >> 1)*32;
      short8 ak0 = *(const short8*)&Kbuf[R*64 + slot0];
      short8 ak1 = *(const short8*)&Kbuf[R*64 + slot1];
      f32x4 z = {};
      z = __builtin_amdgcn_mfma_f32_16x16x32_bf16(ak0, aq[0], z, 0, 0, 0);
      z = __builtin_amdgcn_mfma_f32_16x16x32_bf16(ak1, aq[1], z, 0, 0, 0);
      float p0 = EXP2(z[0]), p1 = EXP2(z[1]);
      float p2 = EXP2(z[2]), p3 = EXP2(z[3]);
      lsum += (p0 + p1) + (p2 + p3);
      Wp[nf >> 1][nf & 1][0] = pk2(p0, p1);
      Wp[nf >> 1][nf & 1][1] = pk2(p2, p3);
    }
    __builtin_amdgcn_s_setprio(0);
    short8 pa[2];
#pragma unroll
    for (int c=0; c<2; ++c){
      union { uint32_t u[4]; short8 s; } tt;
      tt.u[0] = Wp[c][0][0]; tt.u[1] = Wp[c][0][1];
      tt.u[2] = Wp[c][1][0]; tt.u[3] = Wp[c][1][1];
      pa[c] = tt.s;
    }
    // PV: O += P·V, V B-frags straight from swizzled VhT tile
    const short* Vbuf = &Vl[buf][0];
    __builtin_amdgcn_s_setprio(1);
#pragma unroll
    for (int df=0; df<4; ++df){
      int rowv = (df*16 + lr)*64;
      short8 vb0 = *(const short8*)&Vbuf[rowv + ((lg ^ vx) << 3)];
      short8 vb1 = *(const short8*)&Vbuf[rowv + (((4 + lg) ^ vx) << 3)];
      o[df] = __builtin_amdgcn_mfma_f32_16x16x32_bf16(pa[0], vb0, o[df], 0, 0, 0);
      o[df] = __builtin_amdgcn_mfma_f32_16x16x32_bf16(pa[1], vb1, o[df], 0, 0, 0);
    }
    __builtin_amdgcn_s_setprio(0);
    if (t + 1 < 32){
      // counted vmcnt: tile t+1's K,V complete; tile t+2's 2 loads stay in flight
      if (t < 30) asm volatile("s_waitcnt vmcnt(2)" ::: "memory");
      else        asm volatile("s_waitcnt vmcnt(0)" ::: "memory");
      __builtin_amdgcn_sched_barrier(0);
      __builtin_amdgcn_s_barrier();
    }
  }
  // epilogue: reduce lsum across k-slice groups, normalize, write AO[b][s][h*64+d]
  lsum += __shfl_xor(lsum, 16); lsum += __shfl_xor(lsum, 32);
  int b = bh >> 4, hh = bh & 15;
  float rinv[4];
#pragma unroll
  for (int i2=0; i2<4; ++i2) rinv[i2] = 1.0f / __shfl(lsum, (lg << 2) + i2);
#pragma unroll
  for (int df=0; df<4; ++df)
#pragma unroll
    for (int i2=0; i2<4; ++i2){
      int row = q0 + lg*4 + i2;
      int col = df*16 + lr;
      AO[((size_t)(b*2048 + row))*1024 + hh*64 + col] = f2bf(o[df][i2] * rinv[i2]);
    }
}

extern "C" void kernel_launch(void* const* d_in, const int* in_sizes, int n_in,
                              void* d_out, int out_size, void* d_ws, size_t ws_size,
                              hipStream_t stream){
  const float* q  = (const float*)d_in[0];
  const float* k  = (const float*)d_in[1];
  const float* v  = (const float*)d_in[2];
  const float* Wq = (const float*)d_in[3];
  const float* bq = (const float*)d_in[4];
  const float* Wk = (const float*)d_in[5];
  const float* bk = (const float*)d_in[6];
  const float* Wv = (const float*)d_in[7];
  const float* bv = (const float*)d_in[8];
  const float* Wo = (const float*)d_in[9];
  const float* bo = (const float*)d_in[10];

  const size_t SQ = 4096ull*1024ull, NW = 1024ull*1024ull;
  short* ws  = (short*)d_ws;
  short* qb  = ws;                    // bf16 q      [4096,1024]
  short* kb  = ws + SQ;
  short* vb  = ws + 2*SQ;
  short* Wqb = ws + 3*SQ;             // bf16 weights [1024,1024]
  short* Wkb = Wqb + NW;
  short* Wvb = Wkb + NW;
  short* Wob = Wvb + NW;
  short* Qh  = Wob + NW;              // [B,H,S,D] bf16 (Q pre-scaled by log2e/8)
  short* Kh  = Qh + SQ;
  short* VhT = Kh + SQ;               // [B,H,D,S] bf16 (transposed V projection)
  short* AO  = qb;                    // reuse q buffer for attention output

  const float Csc = 0.18033688011112042f;   // log2(e)/8

  cvt_all<<<4096, 512, 0, stream>>>(q, k, v, Wq, Wk, Wv, Wo, ws);
  gemm_qkv<<<dim3(16, 32, 3), 512, 0, stream>>>(qb, kb, vb, Wqb, Wkb, Wvb, bq, bk, bv, Qh, Kh, VhT, Csc);
  attn_fwd<<<dim3(16, 32), 512, 0, stream>>>(Qh, Kh, VhT, AO);
  gemm_out<<<dim3(16, 32), 512, 0, stream>>>(AO, Wob, bo, (float*)d_out);
}

// Round 12
// 117.462 us; speedup vs baseline: 1.0857x; 1.0257x over previous
//
#include <hip/hip_runtime.h>
#include <stdint.h>

typedef __attribute__((ext_vector_type(8))) short short8;
typedef __attribute__((ext_vector_type(4))) float f32x4;
typedef __attribute__((ext_vector_type(4))) uint32_t u32x4;

#if __has_builtin(__builtin_amdgcn_exp2f)
#define EXP2(x) __builtin_amdgcn_exp2f(x)
#else
#define EXP2(x) exp2f(x)
#endif

// round-nearest-ties-away bf16: statistically unbiased, 2 VALU ops
__device__ __forceinline__ short f2bf(float f){
  uint32_t u = __builtin_bit_cast(uint32_t, f);
  return (short)((u + 0x8000u) >> 16);
}
// pack two rounded bf16 (lo in low half): 2 adds + 1 v_perm
__device__ __forceinline__ uint32_t pk2(float lo, float hi){
  uint32_t a = __builtin_bit_cast(uint32_t, lo) + 0x8000u;
  uint32_t b = __builtin_bit_cast(uint32_t, hi) + 0x8000u;
#if __has_builtin(__builtin_amdgcn_perm)
  return __builtin_amdgcn_perm(b, a, 0x07060302u);   // [b3 b2 a3 a2]
#else
  return (b & 0xFFFF0000u) | (a >> 16);
#endif
}
__device__ __forceinline__ void gload16(const void* g, void* l){
  __builtin_amdgcn_global_load_lds((const __attribute__((address_space(1))) void*)g,
                                   (__attribute__((address_space(3))) void*)l, 16, 0, 0);
}

// ---------------- fp32 -> bf16 conversion of q,k,v,Wq,Wk,Wv,Wo ----------------
__global__ __launch_bounds__(512) void cvt_all(
    const float* __restrict__ q, const float* __restrict__ k, const float* __restrict__ v,
    const float* __restrict__ wq, const float* __restrict__ wk, const float* __restrict__ wv,
    const float* __restrict__ wo, short* __restrict__ dst){
  const size_t SQ = 4096ull*1024ull, NW = 1024ull*1024ull;
  size_t e = (size_t)(blockIdx.x*512u + threadIdx.x)*8ull;
  const float* src; size_t rel;
  if (e < 3*SQ){ size_t which = e / SQ; src = which==0?q:(which==1?k:v); rel = e - which*SQ; }
  else { size_t e2 = e - 3*SQ; size_t which = e2 / NW;
         src = which==0?wq:(which==1?wk:(which==2?wv:wo)); rel = e2 - which*NW; }
  float4 a = *(const float4*)(src + rel);
  float4 b = *(const float4*)(src + rel + 4);
  u32x4 r = { pk2(a.x,a.y), pk2(a.z,a.w), pk2(b.x,b.y), pk2(b.z,b.w) };
  *(u32x4*)(dst + e) = r;
}

// ---------------- NT GEMM core: 128x128 tile, BK=64, 512 thr (2x4 waves), XOR-swizzled LDS ----------------
// MODE 0: bf16 head-scatter [b,h,s,d]. MODE 1: f32 linear. MODE 2: bf16 transposed head-scatter [b,h,d,s].
template<int MODE>
__device__ __forceinline__ void gemm_body(const short* __restrict__ A, const short* __restrict__ Bw,
    const float* __restrict__ bias, void* __restrict__ Cout, float scale, int m0, int n0){
  const int K = 1024;
  __shared__ short Al[128*64];
  __shared__ short Bl[128*64];
  int tid = threadIdx.x;
  int w = tid >> 6, lane = tid & 63, lr = lane & 15, lg = lane >> 4;
  int wr = w >> 2, wc = w & 3;               // 2 x 4 wave grid
  f32x4 acc[4][2] = {};
  int row0 = tid >> 3;                       // 0..63
  int qc0  = (tid & 7) ^ (row0 & 7);
  const short* Ag = A  + (size_t)(m0 + row0)*K + qc0*8;
  const short* Bg = Bw + (size_t)(n0 + row0)*K + qc0*8;
  char* Alb = (char*)Al + tid*16;
  char* Blb = (char*)Bl + tid*16;
  int ra[4], rb[2];
#pragma unroll
  for (int mi=0; mi<4; ++mi) ra[mi] = wr*64 + mi*16 + lr;
#pragma unroll
  for (int ni=0; ni<2; ++ni) rb[ni] = wc*32 + ni*16 + lr;
  for (int k0 = 0; k0 < K; k0 += 64){
    gload16(Ag + k0,                Alb);
    gload16(Ag + k0 + 64*(size_t)K, Alb + 8192);
    gload16(Bg + k0,                Blb);
    gload16(Bg + k0 + 64*(size_t)K, Blb + 8192);
    __syncthreads();
#pragma unroll
    for (int kk=0; kk<2; ++kk){
      short8 av[4], bv[2];
#pragma unroll
      for (int mi=0; mi<4; ++mi)
        av[mi] = *(const short8*)((char*)Al + ra[mi]*128 + (((kk*4 + lg) ^ (ra[mi] & 7)) << 4));
#pragma unroll
      for (int ni=0; ni<2; ++ni)
        bv[ni] = *(const short8*)((char*)Bl + rb[ni]*128 + (((kk*4 + lg) ^ (rb[ni] & 7)) << 4));
#pragma unroll
      for (int mi=0; mi<4; ++mi)
#pragma unroll
        for (int ni=0; ni<2; ++ni)
          acc[mi][ni] = __builtin_amdgcn_mfma_f32_16x16x32_bf16(av[mi], bv[ni], acc[mi][ni], 0, 0, 0);
    }
    __syncthreads();
  }
#pragma unroll
  for (int ni=0; ni<2; ++ni){
    int col = n0 + wc*32 + ni*16 + lr;
    float bb = bias[col];
#pragma unroll
    for (int mi=0; mi<4; ++mi){
      if (MODE == 2){
        // transposed per-head scatter: 4 consecutive s for one d -> one 8B store
        int row = m0 + wr*64 + mi*16 + lg*4;
        int b = row >> 11, s = row & 2047, h = col >> 6, d = col & 63;
        uint2 val;
        val.x = pk2((acc[mi][ni][0] + bb)*scale, (acc[mi][ni][1] + bb)*scale);
        val.y = pk2((acc[mi][ni][2] + bb)*scale, (acc[mi][ni][3] + bb)*scale);
        *(uint2*)&((short*)Cout)[(((size_t)(b*16 + h))*64 + d)*2048 + s] = val;
      } else {
#pragma unroll
        for (int i2=0; i2<4; ++i2){
          int row = m0 + wr*64 + mi*16 + lg*4 + i2;
          float val = (acc[mi][ni][i2] + bb) * scale;
          if (MODE == 0){
            int b = row >> 11, s = row & 2047, h = col >> 6, d = col & 63;
            ((short*)Cout)[(((size_t)(b*16 + h))*2048 + s)*64 + d] = f2bf(val);
          } else {
            ((float*)Cout)[(size_t)row*1024 + col] = val;
          }
        }
      }
    }
  }
}

__global__ __launch_bounds__(512) void gemm_qkv(
    const short* __restrict__ qb, const short* __restrict__ kb, const short* __restrict__ vb,
    const short* __restrict__ Wqb, const short* __restrict__ Wkb, const short* __restrict__ Wvb,
    const float* __restrict__ bq, const float* __restrict__ bk, const float* __restrict__ bv,
    short* __restrict__ Qh, short* __restrict__ Kh, short* __restrict__ VhT, float qscale){
  int f = blockIdx.y*gridDim.x + blockIdx.x;              // 0..767
  int L = (f & 7)*96 + (f >> 3);                          // XCD-contiguous (768 % 8 == 0)
  int z = L >> 8, r = L & 255;
  int m0 = (r >> 3)*128, n0 = (r & 7)*128;
  const short* A  = z==0 ? qb  : (z==1 ? kb  : vb);
  const short* Bw = z==0 ? Wqb : (z==1 ? Wkb : Wvb);
  const float* bi = z==0 ? bq  : (z==1 ? bk  : bv);
  short* C        = z==0 ? Qh  : (z==1 ? Kh  : VhT);
  if (z == 2) gemm_body<2>(A, Bw, bi, (void*)C, 1.0f, m0, n0);
  else        gemm_body<0>(A, Bw, bi, (void*)C, z==0 ? qscale : 1.0f, m0, n0);
}

__global__ __launch_bounds__(512) void gemm_out(const short* __restrict__ A, const short* __restrict__ Bw,
    const float* __restrict__ bias, float* __restrict__ Cout){
  int f = blockIdx.y*gridDim.x + blockIdx.x;              // 0..255
  int L = (f & 7)*32 + (f >> 3);
  int m0 = (L >> 3)*128, n0 = (L & 7)*128;
  gemm_body<1>(A, Bw, bias, (void*)Cout, 1.0f, m0, n0);
}

// ---------------- flash attention: 8 waves x 16 q-rows, register P, 4-buffer counted-vmcnt ----------------
// Swapped QK^T with permuted K-rows (R6-verified): iteration nf covers K rows
// R = 32*(nf>>1) + 8*(lr>>2) + 4*(nf&1) + (lr&3); lane(lg) accumulates scores for
// k = 32c + 8*lg + 4*(nf&1) + i2 — exactly the PV A-fragment set (P never leaves regs).
// V pre-transposed by gemm_qkv (VhT[b,h,d,s]) -> staged like K; PV B-frag = ds_read_b128.
// lsum computed by 2 extra MFMAs with an all-ones B (accumulator layout == o) -> no VALU adds,
// no epilogue shuffles. Q pre-scaled by log2(e)/8, so p = exp2(z) directly.
__global__ __launch_bounds__(512) void attn_fwd(const short* __restrict__ Qh, const short* __restrict__ Kh,
    const short* __restrict__ VhT, short* __restrict__ AO){
  const int S = 2048;
  int i = blockIdx.y*gridDim.x + blockIdx.x;   // 512 wgs
  int L = (i & 7)*64 + (i >> 3);
  int bh = L >> 4, qt = L & 15;
  __shared__ short Kl[4][4096];      // 4-buffer K; read-slot swizzle, source-side
  __shared__ short Vl[4][4096];      // 4-buffer V^T[d][k-chunk ^ (d&7)]
  int tid = threadIdx.x, w = tid >> 6, lane = tid & 63, lr = lane & 15, lg = lane >> 4;
  const short* Qb = Qh  + (size_t)bh*S*64;
  const short* Kb = Kh  + (size_t)bh*S*64;
  const short* Vb = VhT + (size_t)bh*64*2048;   // 64 d-rows of length S
  int q0 = qt*128 + w*16;
  short8 aq[2];
#pragma unroll
  for (int h=0; h<2; ++h)
    aq[h] = *(const short8*)&Qb[(size_t)(q0 + lr)*64 + h*32 + lg*8];
  f32x4 o[4] = {};
  f32x4 o1 = {};                      // row-sums of P via ones-MFMA
  short8 ones;
#pragma unroll
  for (int j=0; j<8; ++j) ones[j] = (short)0x3F80;   // bf16 1.0
  // K staging: 1 gload16/thread; LDS dest linear, source pre-swizzled
  int koff = tid*16;
  int kr = tid >> 3, kc = tid & 7;
  int ksw = (kr & 3) | (((kr >> 3) & 1) << 2);
  int ksrc = kr*64 + ((kc ^ ksw) << 3);
  // V staging: 1 gload16/thread; row d = tid>>3 (stride 2048), chunk XOR by d&7
  int vsrc = kr*2048 + ((kc ^ (kr & 7)) << 3);
  // K read addressing
  int Rbase = 8*(lr >> 2) + (lr & 3);
  int sR = (lr & 3) | (((lr >> 2) & 1) << 2);
  int slot0 = (lg ^ sR) << 3, slot1 = ((lg + 4) ^ sR) << 3;
  // V read addressing: chunk xor term
  int vx = lr & 7;
  // ---- prologue: K/V tiles 0 and 1 ----
  gload16(Kb + ksrc,        (char*)&Kl[0][0] + koff);
  gload16(Vb + vsrc,        (char*)&Vl[0][0] + koff);
  gload16(Kb + 4096 + ksrc, (char*)&Kl[1][0] + koff);
  gload16(Vb + vsrc + 64,   (char*)&Vl[1][0] + koff);
  asm volatile("s_waitcnt vmcnt(2) lgkmcnt(0)" ::: "memory");  // tile 0 landed; tile 1 in flight
  __builtin_amdgcn_sched_barrier(0);
  __builtin_amdgcn_s_barrier();

  for (int t = 0; t < 32; ++t){
    int buf = t & 3;
    if (t + 2 < 32){
      int nb = (t + 2) & 3;
      gload16(Kb + (size_t)(t + 2)*4096 + ksrc, (char*)&Kl[nb][0] + koff);
      gload16(Vb + vsrc + (t + 2)*64,           (char*)&Vl[nb][0] + koff);
    }
    // QK^T (swapped, permuted K-rows) + exp2; P accumulates into A-fragment registers
    const short* Kbuf = &Kl[buf][0];
    uint32_t Wp[2][2][2];   // [c][nf0][s]
    __builtin_amdgcn_s_setprio(1);
#pragma unroll
    for (int nf=0; nf<4; ++nf){
      int R = Rbase + (nf & 1)*4 + (nf >> 1)*32;
      short8 ak0 = *(const short8*)&Kbuf[R*64 + slot0];
      short8 ak1 = *(const short8*)&Kbuf[R*64 + slot1];
      f32x4 z = {};
      z = __builtin_amdgcn_mfma_f32_16x16x32_bf16(ak0, aq[0], z, 0, 0, 0);
      z = __builtin_amdgcn_mfma_f32_16x16x32_bf16(ak1, aq[1], z, 0, 0, 0);
      float p0 = EXP2(z[0]), p1 = EXP2(z[1]);
      float p2 = EXP2(z[2]), p3 = EXP2(z[3]);
      Wp[nf >> 1][nf & 1][0] = pk2(p0, p1);
      Wp[nf >> 1][nf & 1][1] = pk2(p2, p3);
    }
    __builtin_amdgcn_s_setprio(0);
    short8 pa[2];
#pragma unroll
    for (int c=0; c<2; ++c){
      union { uint32_t u[4]; short8 s; } tt;
      tt.u[0] = Wp[c][0][0]; tt.u[1] = Wp[c][0][1];
      tt.u[2] = Wp[c][1][0]; tt.u[3] = Wp[c][1][1];
      pa[c] = tt.s;
    }
    // PV: O += P·V, V B-frags straight from swizzled VhT tile; o1 += P·1 (row sums)
    const short* Vbuf = &Vl[buf][0];
    __builtin_amdgcn_s_setprio(1);
#pragma unroll
    for (int df=0; df<4; ++df){
      int rowv = (df*16 + lr)*64;
      short8 vb0 = *(const short8*)&Vbuf[rowv + ((lg ^ vx) << 3)];
      short8 vb1 = *(const short8*)&Vbuf[rowv + (((4 + lg) ^ vx) << 3)];
      o[df] = __builtin_amdgcn_mfma_f32_16x16x32_bf16(pa[0], vb0, o[df], 0, 0, 0);
      o[df] = __builtin_amdgcn_mfma_f32_16x16x32_bf16(pa[1], vb1, o[df], 0, 0, 0);
    }
    o1 = __builtin_amdgcn_mfma_f32_16x16x32_bf16(pa[0], ones, o1, 0, 0, 0);
    o1 = __builtin_amdgcn_mfma_f32_16x16x32_bf16(pa[1], ones, o1, 0, 0, 0);
    __builtin_amdgcn_s_setprio(0);
    if (t + 1 < 32){
      // counted vmcnt: tile t+1's K,V complete; tile t+2's 2 loads stay in flight
      if (t < 30) asm volatile("s_waitcnt vmcnt(2)" ::: "memory");
      else        asm volatile("s_waitcnt vmcnt(0)" ::: "memory");
      __builtin_amdgcn_sched_barrier(0);
      __builtin_amdgcn_s_barrier();
    }
  }
  // epilogue: normalize by MFMA-computed row sums, write AO[b][s][h*64+d]
  int b = bh >> 4, hh = bh & 15;
  float rinv[4];
#pragma unroll
  for (int i2=0; i2<4; ++i2) rinv[i2] = 1.0f / o1[i2];
#pragma unroll
  for (int df=0; df<4; ++df)
#pragma unroll
    for (int i2=0; i2<4; ++i2){
      int row = q0 + lg*4 + i2;
      int col = df*16 + lr;
      AO[((size_t)(b*2048 + row))*1024 + hh*64 + col] = f2bf(o[df][i2] * rinv[i2]);
    }
}

extern "C" void kernel_launch(void* const* d_in, const int* in_sizes, int n_in,
                              void* d_out, int out_size, void* d_ws, size_t ws_size,
                              hipStream_t stream){
  const float* q  = (const float*)d_in[0];
  const float* k  = (const float*)d_in[1];
  const float* v  = (const float*)d_in[2];
  const float* Wq = (const float*)d_in[3];
  const float* bq = (const float*)d_in[4];
  const float* Wk = (const float*)d_in[5];
  const float* bk = (const float*)d_in[6];
  const float* Wv = (const float*)d_in[7];
  const float* bv = (const float*)d_in[8];
  const float* Wo = (const float*)d_in[9];
  const float* bo = (const float*)d_in[10];

  const size_t SQ = 4096ull*1024ull, NW = 1024ull*1024ull;
  short* ws  = (short*)d_ws;
  short* qb  = ws;                    // bf16 q      [4096,1024]
  short* kb  = ws + SQ;
  short* vb  = ws + 2*SQ;
  short* Wqb = ws + 3*SQ;             // bf16 weights [1024,1024]
  short* Wkb = Wqb + NW;
  short* Wvb = Wkb + NW;
  short* Wob = Wvb + NW;
  short* Qh  = Wob + NW;              // [B,H,S,D] bf16 (Q pre-scaled by log2e/8)
  short* Kh  = Qh + SQ;
  short* VhT = Kh + SQ;               // [B,H,D,S] bf16 (transposed V projection)
  short* AO  = qb;                    // reuse q buffer for attention output

  const float Csc = 0.18033688011112042f;   // log2(e)/8

  cvt_all<<<4096, 512, 0, stream>>>(q, k, v, Wq, Wk, Wv, Wo, ws);
  gemm_qkv<<<dim3(16, 48), 512, 0, stream>>>(qb, kb, vb, Wqb, Wkb, Wvb, bq, bk, bv, Qh, Kh, VhT, Csc);
  attn_fwd<<<dim3(16, 32), 512, 0, stream>>>(Qh, Kh, VhT, AO);
  gemm_out<<<dim3(16, 16), 512, 0, stream>>>(AO, Wob, bo, (float*)d_out);
}

// Round 14
// 115.871 us; speedup vs baseline: 1.1006x; 1.0137x over previous
//
#include <hip/hip_runtime.h>
#include <hip/hip_bf16.h>
#include <stdint.h>

typedef __attribute__((ext_vector_type(8))) short short8;
typedef __attribute__((ext_vector_type(4))) float f32x4;
typedef __attribute__((ext_vector_type(4))) uint32_t u32x4;

#if __has_builtin(__builtin_amdgcn_exp2f)
#define EXP2(x) __builtin_amdgcn_exp2f(x)
#else
#define EXP2(x) exp2f(x)
#endif

// round-nearest-ties-away bf16 (scalar stores): 2 VALU ops, statistically unbiased
__device__ __forceinline__ short f2bf(float f){
  uint32_t u = __builtin_bit_cast(uint32_t, f);
  return (short)((u + 0x8000u) >> 16);
}
// RNE pack of two f32 -> u32 (lo in low half) via compiler-lowered cvt_pk
__device__ __forceinline__ uint32_t pk2(float lo, float hi){
  __hip_bfloat162 h = __float22bfloat162_rn(make_float2(lo, hi));
  uint32_t u; __builtin_memcpy(&u, &h, 4); return u;
}
__device__ __forceinline__ void gload16(const void* g, void* l){
  __builtin_amdgcn_global_load_lds((const __attribute__((address_space(1))) void*)g,
                                   (__attribute__((address_space(3))) void*)l, 16, 0, 0);
}

// ---------------- fp32 -> bf16 conversion of q,k,v,Wq,Wk,Wv,Wo ----------------
__global__ __launch_bounds__(512) void cvt_all(
    const float* __restrict__ q, const float* __restrict__ k, const float* __restrict__ v,
    const float* __restrict__ wq, const float* __restrict__ wk, const float* __restrict__ wv,
    const float* __restrict__ wo, short* __restrict__ dst){
  const size_t SQ = 4096ull*1024ull, NW = 1024ull*1024ull;
  size_t e = (size_t)(blockIdx.x*512u + threadIdx.x)*8ull;
  const float* src; size_t rel;
  if (e < 3*SQ){ size_t which = e / SQ; src = which==0?q:(which==1?k:v); rel = e - which*SQ; }
  else { size_t e2 = e - 3*SQ; size_t which = e2 / NW;
         src = which==0?wq:(which==1?wk:(which==2?wv:wo)); rel = e2 - which*NW; }
  float4 a = *(const float4*)(src + rel);
  float4 b = *(const float4*)(src + rel + 4);
  u32x4 r = { pk2(a.x,a.y), pk2(a.z,a.w), pk2(b.x,b.y), pk2(b.z,b.w) };
  *(u32x4*)(dst + e) = r;
}

// ---------------- NT GEMM core: 128x128 tile, BK=64, 512 thr (2x4 waves), XOR-swizzled LDS ----------------
// MODE 0: bf16 head-scatter [b,h,s,d]. MODE 1: f32 linear.
// MODE 2: bf16 transposed head-scatter [b,h,d,s] via operand-swapped MFMA (D = C^T natively).
template<int MODE>
__device__ __forceinline__ void gemm_body(const short* __restrict__ A, const short* __restrict__ Bw,
    const float* __restrict__ bias, void* __restrict__ Cout, float scale, int m0, int n0){
  const int K = 1024;
  __shared__ short Al[128*64];
  __shared__ short Bl[128*64];
  int tid = threadIdx.x;
  int w = tid >> 6, lane = tid & 63, lr = lane & 15, lg = lane >> 4;
  int wr = w >> 2, wc = w & 3;               // 2 x 4 wave grid
  f32x4 acc[4][2] = {};
  int row0 = tid >> 3;                       // 0..63
  int qc0  = (tid & 7) ^ (row0 & 7);
  const short* Ag = A  + (size_t)(m0 + row0)*K + qc0*8;
  const short* Bg = Bw + (size_t)(n0 + row0)*K + qc0*8;
  char* Alb = (char*)Al + tid*16;
  char* Blb = (char*)Bl + tid*16;
  int ra[4], rb[2];
#pragma unroll
  for (int mi=0; mi<4; ++mi) ra[mi] = wr*64 + mi*16 + lr;
#pragma unroll
  for (int ni=0; ni<2; ++ni) rb[ni] = wc*32 + ni*16 + lr;
  for (int k0 = 0; k0 < K; k0 += 64){
    gload16(Ag + k0,                Alb);
    gload16(Ag + k0 + 64*(size_t)K, Alb + 8192);
    gload16(Bg + k0,                Blb);
    gload16(Bg + k0 + 64*(size_t)K, Blb + 8192);
    __syncthreads();
#pragma unroll
    for (int kk=0; kk<2; ++kk){
      short8 av[4], bv[2];
#pragma unroll
      for (int mi=0; mi<4; ++mi)
        av[mi] = *(const short8*)((char*)Al + ra[mi]*128 + (((kk*4 + lg) ^ (ra[mi] & 7)) << 4));
#pragma unroll
      for (int ni=0; ni<2; ++ni)
        bv[ni] = *(const short8*)((char*)Bl + rb[ni]*128 + (((kk*4 + lg) ^ (rb[ni] & 7)) << 4));
#pragma unroll
      for (int mi=0; mi<4; ++mi)
#pragma unroll
        for (int ni=0; ni<2; ++ni){
          if (MODE == 2)
            acc[mi][ni] = __builtin_amdgcn_mfma_f32_16x16x32_bf16(bv[ni], av[mi], acc[mi][ni], 0, 0, 0);
          else
            acc[mi][ni] = __builtin_amdgcn_mfma_f32_16x16x32_bf16(av[mi], bv[ni], acc[mi][ni], 0, 0, 0);
        }
    }
    __syncthreads();
  }
#pragma unroll
  for (int ni=0; ni<2; ++ni){
#pragma unroll
    for (int mi=0; mi<4; ++mi){
      if (MODE == 2){
        // D = C^T: fragment row = d-dim, col = s-dim. 16 consecutive s per lr-group -> 32B segments.
        int srow = m0 + wr*64 + mi*16 + lr;
        int b = srow >> 11, s = srow & 2047;
#pragma unroll
        for (int i2=0; i2<4; ++i2){
          int dcol = n0 + wc*32 + ni*16 + lg*4 + i2;
          int h = dcol >> 6, d = dcol & 63;
          float val = acc[mi][ni][i2] + bias[dcol];
          ((short*)Cout)[(((size_t)(b*16 + h))*64 + d)*2048 + s] = f2bf(val);
        }
      } else {
        int col = n0 + wc*32 + ni*16 + lr;
        float bb = bias[col];
#pragma unroll
        for (int i2=0; i2<4; ++i2){
          int row = m0 + wr*64 + mi*16 + lg*4 + i2;
          float val = (acc[mi][ni][i2] + bb) * scale;
          if (MODE == 0){
            int b = row >> 11, s = row & 2047, h = col >> 6, d = col & 63;
            ((short*)Cout)[(((size_t)(b*16 + h))*2048 + s)*64 + d] = f2bf(val);
          } else {
            ((float*)Cout)[(size_t)row*1024 + col] = val;
          }
        }
      }
    }
  }
}

__global__ __launch_bounds__(512) void gemm_qkv(
    const short* __restrict__ qb, const short* __restrict__ kb, const short* __restrict__ vb,
    const short* __restrict__ Wqb, const short* __restrict__ Wkb, const short* __restrict__ Wvb,
    const float* __restrict__ bq, const float* __restrict__ bk, const float* __restrict__ bv,
    short* __restrict__ Qh, short* __restrict__ Kh, short* __restrict__ VhT, float qscale){
  int f = blockIdx.y*gridDim.x + blockIdx.x;              // 0..767
  int L = (f & 7)*96 + (f >> 3);                          // XCD-contiguous (768 % 8 == 0)
  int z = L >> 8, r = L & 255;
  int m0 = (r >> 3)*128, n0 = (r & 7)*128;
  const short* A  = z==0 ? qb  : (z==1 ? kb  : vb);
  const short* Bw = z==0 ? Wqb : (z==1 ? Wkb : Wvb);
  const float* bi = z==0 ? bq  : (z==1 ? bk  : bv);
  short* C        = z==0 ? Qh  : (z==1 ? Kh  : VhT);
  if (z == 2) gemm_body<2>(A, Bw, bi, (void*)C, 1.0f, m0, n0);
  else        gemm_body<0>(A, Bw, bi, (void*)C, z==0 ? qscale : 1.0f, m0, n0);
}

__global__ __launch_bounds__(512) void gemm_out(const short* __restrict__ A, const short* __restrict__ Bw,
    const float* __restrict__ bias, float* __restrict__ Cout){
  int f = blockIdx.y*gridDim.x + blockIdx.x;              // 0..255
  int L = (f & 7)*32 + (f >> 3);
  int m0 = (L >> 3)*128, n0 = (L & 7)*128;
  gemm_body<1>(A, Bw, bias, (void*)Cout, 1.0f, m0, n0);
}

// ---------------- flash attention: 8 waves x 16 q-rows, register P, 4-buffer counted-vmcnt ----------------
// Swapped QK^T with permuted K-rows (R6-verified): iteration nf covers K rows
// R = 32*(nf>>1) + 8*(lr>>2) + 4*(nf&1) + (lr&3); lane(lg) accumulates scores for
// k = 32c + 8*lg + 4*(nf&1) + i2 — exactly the PV A-fragment set (P never leaves regs).
// V pre-transposed by gemm_qkv (VhT[b,h,d,s]) -> staged like K; PV B-frag = ds_read_b128.
// lsum via 2 ones-MFMAs (accumulator layout == o). Q pre-scaled by log2(e)/8 -> p = exp2(z).
__global__ __launch_bounds__(512) void attn_fwd(const short* __restrict__ Qh, const short* __restrict__ Kh,
    const short* __restrict__ VhT, short* __restrict__ AO){
  const int S = 2048;
  int i = blockIdx.y*gridDim.x + blockIdx.x;   // 512 wgs
  int L = (i & 7)*64 + (i >> 3);
  int bh = L >> 4, qt = L & 15;
  __shared__ short Kl[4][4096];      // 4-buffer K; read-slot swizzle, source-side
  __shared__ short Vl[4][4096];      // 4-buffer V^T[d][k-chunk ^ (d&7)]
  int tid = threadIdx.x, w = tid >> 6, lane = tid & 63, lr = lane & 15, lg = lane >> 4;
  const short* Qb = Qh  + (size_t)bh*S*64;
  const short* Kb = Kh  + (size_t)bh*S*64;
  const short* Vb = VhT + (size_t)bh*64*2048;   // 64 d-rows of length S
  int q0 = qt*128 + w*16;
  short8 aq[2];
#pragma unroll
  for (int h=0; h<2; ++h)
    aq[h] = *(const short8*)&Qb[(size_t)(q0 + lr)*64 + h*32 + lg*8];
  f32x4 o[4] = {};
  f32x4 o1 = {};                      // row-sums of P via ones-MFMA
  short8 ones;
#pragma unroll
  for (int j=0; j<8; ++j) ones[j] = (short)0x3F80;   // bf16 1.0
  // K staging: 1 gload16/thread; LDS dest linear, source pre-swizzled
  int koff = tid*16;
  int kr = tid >> 3, kc = tid & 7;
  int ksw = (kr & 3) | (((kr >> 3) & 1) << 2);
  int ksrc = kr*64 + ((kc ^ ksw) << 3);
  // V staging: 1 gload16/thread; row d = tid>>3 (stride 2048), chunk XOR by d&7
  int vsrc = kr*2048 + ((kc ^ (kr & 7)) << 3);
  // K read addressing
  int Rbase = 8*(lr >> 2) + (lr & 3);
  int sR = (lr & 3) | (((lr >> 2) & 1) << 2);
  int slot0 = (lg ^ sR) << 3, slot1 = ((lg + 4) ^ sR) << 3;
  // V read addressing: chunk xor term
  int vx = lr & 7;
  // ---- prologue: K/V tiles 0 and 1 ----
  gload16(Kb + ksrc,        (char*)&Kl[0][0] + koff);
  gload16(Vb + vsrc,        (char*)&Vl[0][0] + koff);
  gload16(Kb + 4096 + ksrc, (char*)&Kl[1][0] + koff);
  gload16(Vb + vsrc + 64,   (char*)&Vl[1][0] + koff);
  asm volatile("s_waitcnt vmcnt(2) lgkmcnt(0)" ::: "memory");  // tile 0 landed; tile 1 in flight
  __builtin_amdgcn_sched_barrier(0);
  __builtin_amdgcn_s_barrier();

  for (int t = 0; t < 32; ++t){
    int buf = t & 3;
    if (t + 2 < 32){
      int nb = (t + 2) & 3;
      gload16(Kb + (size_t)(t + 2)*4096 + ksrc, (char*)&Kl[nb][0] + koff);
      gload16(Vb + vsrc + (t + 2)*64,           (char*)&Vl[nb][0] + koff);
    }
    // QK^T (swapped, permuted K-rows) + exp2; P accumulates into A-fragment registers
    const short* Kbuf = &Kl[buf][0];
    uint32_t Wp[2][2][2];   // [c][nf0][s]
    __builtin_amdgcn_s_setprio(1);
#pragma unroll
    for (int nf=0; nf<4; ++nf){
      int R = Rbase + (nf & 1)*4 + (nf >> 1)*32;
      short8 ak0 = *(const short8*)&Kbuf[R*64 + slot0];
      short8 ak1 = *(const short8*)&Kbuf[R*64 + slot1];
      f32x4 z = {};
      z = __builtin_amdgcn_mfma_f32_16x16x32_bf16(ak0, aq[0], z, 0, 0, 0);
      z = __builtin_amdgcn_mfma_f32_16x16x32_bf16(ak1, aq[1], z, 0, 0, 0);
      float p0 = EXP2(z[0]), p1 = EXP2(z[1]);
      float p2 = EXP2(z[2]), p3 = EXP2(z[3]);
      Wp[nf >> 1][nf & 1][0] = pk2(p0, p1);
      Wp[nf >> 1][nf & 1][1] = pk2(p2, p3);
    }
    __builtin_amdgcn_s_setprio(0);
    short8 pa[2];
#pragma unroll
    for (int c=0; c<2; ++c){
      union { uint32_t u[4]; short8 s; } tt;
      tt.u[0] = Wp[c][0][0]; tt.u[1] = Wp[c][0][1];
      tt.u[2] = Wp[c][1][0]; tt.u[3] = Wp[c][1][1];
      pa[c] = tt.s;
    }
    // PV: O += P·V, V B-frags straight from swizzled VhT tile; o1 += P·1 (row sums)
    const short* Vbuf = &Vl[buf][0];
    __builtin_amdgcn_s_setprio(1);
#pragma unroll
    for (int df=0; df<4; ++df){
      int rowv = (df*16 + lr)*64;
      short8 vb0 = *(const short8*)&Vbuf[rowv + ((lg ^ vx) << 3)];
      short8 vb1 = *(const short8*)&Vbuf[rowv + (((4 + lg) ^ vx) << 3)];
      o[df] = __builtin_amdgcn_mfma_f32_16x16x32_bf16(pa[0], vb0, o[df], 0, 0, 0);
      o[df] = __builtin_amdgcn_mfma_f32_16x16x32_bf16(pa[1], vb1, o[df], 0, 0, 0);
    }
    o1 = __builtin_amdgcn_mfma_f32_16x16x32_bf16(pa[0], ones, o1, 0, 0, 0);
    o1 = __builtin_amdgcn_mfma_f32_16x16x32_bf16(pa[1], ones, o1, 0, 0, 0);
    __builtin_amdgcn_s_setprio(0);
    if (t + 1 < 32){
      // counted vmcnt: tile t+1's K,V complete; tile t+2's 2 loads stay in flight
      if (t < 30) asm volatile("s_waitcnt vmcnt(2)" ::: "memory");
      else        asm volatile("s_waitcnt vmcnt(0)" ::: "memory");
      __builtin_amdgcn_sched_barrier(0);
      __builtin_amdgcn_s_barrier();
    }
  }
  // epilogue: normalize by MFMA-computed row sums, write AO[b][s][h*64+d]
  int b = bh >> 4, hh = bh & 15;
  float rinv[4];
#pragma unroll
  for (int i2=0; i2<4; ++i2) rinv[i2] = 1.0f / o1[i2];
#pragma unroll
  for (int df=0; df<4; ++df)
#pragma unroll
    for (int i2=0; i2<4; ++i2){
      int row = q0 + lg*4 + i2;
      int col = df*16 + lr;
      AO[((size_t)(b*2048 + row))*1024 + hh*64 + col] = f2bf(o[df][i2] * rinv[i2]);
    }
}

extern "C" void kernel_launch(void* const* d_in, const int* in_sizes, int n_in,
                              void* d_out, int out_size, void* d_ws, size_t ws_size,
                              hipStream_t stream){
  const float* q  = (const float*)d_in[0];
  const float* k  = (const float*)d_in[1];
  const float* v  = (const float*)d_in[2];
  const float* Wq = (const float*)d_in[3];
  const float* bq = (const float*)d_in[4];
  const float* Wk = (const float*)d_in[5];
  const float* bk = (const float*)d_in[6];
  const float* Wv = (const float*)d_in[7];
  const float* bv = (const float*)d_in[8];
  const float* Wo = (const float*)d_in[9];
  const float* bo = (const float*)d_in[10];

  const size_t SQ = 4096ull*1024ull, NW = 1024ull*1024ull;
  short* ws  = (short*)d_ws;
  short* qb  = ws;                    // bf16 q      [4096,1024]
  short* kb  = ws + SQ;
  short* vb  = ws + 2*SQ;
  short* Wqb = ws + 3*SQ;             // bf16 weights [1024,1024]
  short* Wkb = Wqb + NW;
  short* Wvb = Wkb + NW;
  short* Wob = Wvb + NW;
  short* Qh  = Wob + NW;              // [B,H,S,D] bf16 (Q pre-scaled by log2e/8)
  short* Kh  = Qh + SQ;
  short* VhT = Kh + SQ;               // [B,H,D,S] bf16 (transposed V projection)
  short* AO  = qb;                    // reuse q buffer for attention output

  const float Csc = 0.18033688011112042f;   // log2(e)/8

  cvt_all<<<4096, 512, 0, stream>>>(q, k, v, Wq, Wk, Wv, Wo, ws);
  gemm_qkv<<<dim3(16, 48), 512, 0, stream>>>(qb, kb, vb, Wqb, Wkb, Wvb, bq, bk, bv, Qh, Kh, VhT, Csc);
  attn_fwd<<<dim3(16, 32), 512, 0, stream>>>(Qh, Kh, VhT, AO);
  gemm_out<<<dim3(16, 16), 512, 0, stream>>>(AO, Wob, bo, (float*)d_out);
}

// Round 15
// 114.991 us; speedup vs baseline: 1.1091x; 1.0077x over previous
//
#include <hip/hip_runtime.h>
#include <stdint.h>

typedef __attribute__((ext_vector_type(8))) short short8;
typedef __attribute__((ext_vector_type(4))) float f32x4;
typedef __attribute__((ext_vector_type(4))) uint32_t u32x4;

#if __has_builtin(__builtin_amdgcn_exp2f)
#define EXP2(x) __builtin_amdgcn_exp2f(x)
#else
#define EXP2(x) exp2f(x)
#endif

// round-nearest-ties-away bf16: statistically unbiased, 2 VALU ops
__device__ __forceinline__ short f2bf(float f){
  uint32_t u = __builtin_bit_cast(uint32_t, f);
  return (short)((u + 0x8000u) >> 16);
}
// pack two rounded bf16 (lo in low half): 2 adds + 1 v_perm  (R12-proven fast path)
__device__ __forceinline__ uint32_t pk2(float lo, float hi){
  uint32_t a = __builtin_bit_cast(uint32_t, lo) + 0x8000u;
  uint32_t b = __builtin_bit_cast(uint32_t, hi) + 0x8000u;
#if __has_builtin(__builtin_amdgcn_perm)
  return __builtin_amdgcn_perm(b, a, 0x07060302u);   // [b3 b2 a3 a2]
#else
  return (b & 0xFFFF0000u) | (a >> 16);
#endif
}
__device__ __forceinline__ void gload16(const void* g, void* l){
  __builtin_amdgcn_global_load_lds((const __attribute__((address_space(1))) void*)g,
                                   (__attribute__((address_space(3))) void*)l, 16, 0, 0);
}

// ---------------- fp32 -> bf16 conversion of q,k,v,Wq,Wk,Wv,Wo ----------------
__global__ __launch_bounds__(512) void cvt_all(
    const float* __restrict__ q, const float* __restrict__ k, const float* __restrict__ v,
    const float* __restrict__ wq, const float* __restrict__ wk, const float* __restrict__ wv,
    const float* __restrict__ wo, short* __restrict__ dst){
  const size_t SQ = 4096ull*1024ull, NW = 1024ull*1024ull;
  size_t e = (size_t)(blockIdx.x*512u + threadIdx.x)*8ull;
  const float* src; size_t rel;
  if (e < 3*SQ){ size_t which = e / SQ; src = which==0?q:(which==1?k:v); rel = e - which*SQ; }
  else { size_t e2 = e - 3*SQ; size_t which = e2 / NW;
         src = which==0?wq:(which==1?wk:(which==2?wv:wo)); rel = e2 - which*NW; }
  float4 a = *(const float4*)(src + rel);
  float4 b = *(const float4*)(src + rel + 4);
  u32x4 r = { pk2(a.x,a.y), pk2(a.z,a.w), pk2(b.x,b.y), pk2(b.z,b.w) };
  *(u32x4*)(dst + e) = r;
}

// ---------------- NT GEMM core: 128x128 tile, BK=64, 512 thr (2x4 waves), XOR-swizzled LDS ----------------
// MODE 0: bf16 head-scatter [b,h,s,d]. MODE 1: f32 linear.
// MODE 2: bf16 transposed head-scatter [b,h,d,s] via operand-swapped MFMA (D = C^T natively).
template<int MODE>
__device__ __forceinline__ void gemm_body(const short* __restrict__ A, const short* __restrict__ Bw,
    const float* __restrict__ bias, void* __restrict__ Cout, float scale, int m0, int n0){
  const int K = 1024;
  __shared__ short Al[128*64];
  __shared__ short Bl[128*64];
  int tid = threadIdx.x;
  int w = tid >> 6, lane = tid & 63, lr = lane & 15, lg = lane >> 4;
  int wr = w >> 2, wc = w & 3;               // 2 x 4 wave grid
  f32x4 acc[4][2] = {};
  int row0 = tid >> 3;                       // 0..63
  int qc0  = (tid & 7) ^ (row0 & 7);
  const short* Ag = A  + (size_t)(m0 + row0)*K + qc0*8;
  const short* Bg = Bw + (size_t)(n0 + row0)*K + qc0*8;
  char* Alb = (char*)Al + tid*16;
  char* Blb = (char*)Bl + tid*16;
  int ra[4], rb[2];
#pragma unroll
  for (int mi=0; mi<4; ++mi) ra[mi] = wr*64 + mi*16 + lr;
#pragma unroll
  for (int ni=0; ni<2; ++ni) rb[ni] = wc*32 + ni*16 + lr;
  for (int k0 = 0; k0 < K; k0 += 64){
    gload16(Ag + k0,                Alb);
    gload16(Ag + k0 + 64*(size_t)K, Alb + 8192);
    gload16(Bg + k0,                Blb);
    gload16(Bg + k0 + 64*(size_t)K, Blb + 8192);
    __syncthreads();
#pragma unroll
    for (int kk=0; kk<2; ++kk){
      short8 av[4], bv[2];
#pragma unroll
      for (int mi=0; mi<4; ++mi)
        av[mi] = *(const short8*)((char*)Al + ra[mi]*128 + (((kk*4 + lg) ^ (ra[mi] & 7)) << 4));
#pragma unroll
      for (int ni=0; ni<2; ++ni)
        bv[ni] = *(const short8*)((char*)Bl + rb[ni]*128 + (((kk*4 + lg) ^ (rb[ni] & 7)) << 4));
#pragma unroll
      for (int mi=0; mi<4; ++mi)
#pragma unroll
        for (int ni=0; ni<2; ++ni){
          if (MODE == 2)
            acc[mi][ni] = __builtin_amdgcn_mfma_f32_16x16x32_bf16(bv[ni], av[mi], acc[mi][ni], 0, 0, 0);
          else
            acc[mi][ni] = __builtin_amdgcn_mfma_f32_16x16x32_bf16(av[mi], bv[ni], acc[mi][ni], 0, 0, 0);
        }
    }
    __syncthreads();
  }
#pragma unroll
  for (int ni=0; ni<2; ++ni){
#pragma unroll
    for (int mi=0; mi<4; ++mi){
      if (MODE == 2){
        // D = C^T: fragment row = d-dim, col = s-dim. 16 consecutive s per lr-group -> 32B segments.
        int srow = m0 + wr*64 + mi*16 + lr;
        int b = srow >> 11, s = srow & 2047;
#pragma unroll
        for (int i2=0; i2<4; ++i2){
          int dcol = n0 + wc*32 + ni*16 + lg*4 + i2;
          int h = dcol >> 6, d = dcol & 63;
          float val = acc[mi][ni][i2] + bias[dcol];
          ((short*)Cout)[(((size_t)(b*16 + h))*64 + d)*2048 + s] = f2bf(val);
        }
      } else {
        int col = n0 + wc*32 + ni*16 + lr;
        float bb = bias[col];
#pragma unroll
        for (int i2=0; i2<4; ++i2){
          int row = m0 + wr*64 + mi*16 + lg*4 + i2;
          float val = (acc[mi][ni][i2] + bb) * scale;
          if (MODE == 0){
            int b = row >> 11, s = row & 2047, h = col >> 6, d = col & 63;
            ((short*)Cout)[(((size_t)(b*16 + h))*2048 + s)*64 + d] = f2bf(val);
          } else {
            ((float*)Cout)[(size_t)row*1024 + col] = val;
          }
        }
      }
    }
  }
}

__global__ __launch_bounds__(512) void gemm_qkv(
    const short* __restrict__ qb, const short* __restrict__ kb, const short* __restrict__ vb,
    const short* __restrict__ Wqb, const short* __restrict__ Wkb, const short* __restrict__ Wvb,
    const float* __restrict__ bq, const float* __restrict__ bk, const float* __restrict__ bv,
    short* __restrict__ Qh, short* __restrict__ Kh, short* __restrict__ VhT, float qscale){
  int f = blockIdx.y*gridDim.x + blockIdx.x;              // 0..767
  int L = (f & 7)*96 + (f >> 3);                          // XCD-contiguous (768 % 8 == 0)
  int z = L >> 8, r = L & 255;
  int m0 = (r >> 3)*128, n0 = (r & 7)*128;
  const short* A  = z==0 ? qb  : (z==1 ? kb  : vb);
  const short* Bw = z==0 ? Wqb : (z==1 ? Wkb : Wvb);
  const float* bi = z==0 ? bq  : (z==1 ? bk  : bv);
  short* C        = z==0 ? Qh  : (z==1 ? Kh  : VhT);
  if (z == 2) gemm_body<2>(A, Bw, bi, (void*)C, 1.0f, m0, n0);
  else        gemm_body<0>(A, Bw, bi, (void*)C, z==0 ? qscale : 1.0f, m0, n0);
}

__global__ __launch_bounds__(512) void gemm_out(const short* __restrict__ A, const short* __restrict__ Bw,
    const float* __restrict__ bias, float* __restrict__ Cout){
  int f = blockIdx.y*gridDim.x + blockIdx.x;              // 0..255
  int L = (f & 7)*32 + (f >> 3);
  int m0 = (L >> 3)*128, n0 = (L & 7)*128;
  gemm_body<1>(A, Bw, bias, (void*)Cout, 1.0f, m0, n0);
}

// ---------------- flash attention: 8 waves x 16 q-rows, register P, pair-loop (1 barrier / 2 tiles) ----------------
// Swapped QK^T with permuted K-rows (R6-verified): iteration nf covers K rows
// R = 32*(nf>>1) + 8*(lr>>2) + 4*(nf&1) + (lr&3); lane(lg) accumulates scores for
// k = 32c + 8*lg + 4*(nf&1) + i2 — exactly the PV A-fragment set (P never leaves regs).
// V pre-transposed by gemm_qkv (VhT[b,h,d,s]) -> staged like K; PV B-frag = ds_read_b128.
// lsum via ones-MFMAs. Q pre-scaled by log2(e)/8 -> p = exp2(z).
// Pair-loop schedule: compute tiles {2p,2p+1} -> vmcnt(0) [pair p+1 landed ~7000cy ago]
// -> barrier [bufs of pair p free, p+1 loads globally visible] -> issue pair p+2 into
// pair p's bufs -> next iteration. One barrier per 2 tiles; 2 independent QK/softmax chains.
__global__ __launch_bounds__(512) void attn_fwd(const short* __restrict__ Qh, const short* __restrict__ Kh,
    const short* __restrict__ VhT, short* __restrict__ AO){
  const int S = 2048;
  int i = blockIdx.y*gridDim.x + blockIdx.x;   // 512 wgs
  int L = (i & 7)*64 + (i >> 3);
  int bh = L >> 4, qt = L & 15;
  __shared__ short Kl[4][4096];      // 4-buffer K; read-slot swizzle, source-side
  __shared__ short Vl[4][4096];      // 4-buffer V^T[d][k-chunk ^ (d&7)]
  int tid = threadIdx.x, w = tid >> 6, lane = tid & 63, lr = lane & 15, lg = lane >> 4;
  const short* Qb = Qh  + (size_t)bh*S*64;
  const short* Kb = Kh  + (size_t)bh*S*64;
  const short* Vb = VhT + (size_t)bh*64*2048;   // 64 d-rows of length S
  int q0 = qt*128 + w*16;
  short8 aq[2];
#pragma unroll
  for (int h=0; h<2; ++h)
    aq[h] = *(const short8*)&Qb[(size_t)(q0 + lr)*64 + h*32 + lg*8];
  f32x4 o[4] = {};
  f32x4 o1 = {};                      // row-sums of P via ones-MFMA
  short8 ones;
#pragma unroll
  for (int j=0; j<8; ++j) ones[j] = (short)0x3F80;   // bf16 1.0
  // K staging: 1 gload16/thread; LDS dest linear, source pre-swizzled
  int koff = tid*16;
  int kr = tid >> 3, kc = tid & 7;
  int ksw = (kr & 3) | (((kr >> 3) & 1) << 2);
  int ksrc = kr*64 + ((kc ^ ksw) << 3);
  // V staging: 1 gload16/thread; row d = tid>>3 (stride 2048), chunk XOR by d&7
  int vsrc = kr*2048 + ((kc ^ (kr & 7)) << 3);
  // K read addressing
  int Rbase = 8*(lr >> 2) + (lr & 3);
  int sR = (lr & 3) | (((lr >> 2) & 1) << 2);
  int slot0 = (lg ^ sR) << 3, slot1 = ((lg + 4) ^ sR) << 3;
  // V read addressing: chunk xor term
  int vx = lr & 7;
  // ---- prologue: tiles 0..3 ----
#pragma unroll
  for (int t=0; t<4; ++t){
    gload16(Kb + (size_t)t*4096 + ksrc, (char*)&Kl[t][0] + koff);
    gload16(Vb + vsrc + t*64,           (char*)&Vl[t][0] + koff);
  }
  asm volatile("s_waitcnt vmcnt(4)" ::: "memory");  // tiles 0,1 landed; 2,3 in flight
  __builtin_amdgcn_sched_barrier(0);
  __builtin_amdgcn_s_barrier();

  for (int p = 0; p < 16; ++p){
    short8 pa[2][2];   // [u][c]
    // QK^T + softmax for both tiles of the pair (independent chains)
    __builtin_amdgcn_s_setprio(1);
#pragma unroll
    for (int u = 0; u < 2; ++u){
      const short* Kbuf = &Kl[(2*p + u) & 3][0];
      uint32_t Wp[2][2][2];   // [c][nf0][s]
#pragma unroll
      for (int nf=0; nf<4; ++nf){
        int R = Rbase + (nf & 1)*4 + (nf >> 1)*32;
        short8 ak0 = *(const short8*)&Kbuf[R*64 + slot0];
        short8 ak1 = *(const short8*)&Kbuf[R*64 + slot1];
        f32x4 z = {};
        z = __builtin_amdgcn_mfma_f32_16x16x32_bf16(ak0, aq[0], z, 0, 0, 0);
        z = __builtin_amdgcn_mfma_f32_16x16x32_bf16(ak1, aq[1], z, 0, 0, 0);
        float p0 = EXP2(z[0]), p1 = EXP2(z[1]);
        float p2 = EXP2(z[2]), p3 = EXP2(z[3]);
        Wp[nf >> 1][nf & 1][0] = pk2(p0, p1);
        Wp[nf >> 1][nf & 1][1] = pk2(p2, p3);
      }
#pragma unroll
      for (int c=0; c<2; ++c){
        union { uint32_t u4[4]; short8 s; } tt;
        tt.u4[0] = Wp[c][0][0]; tt.u4[1] = Wp[c][0][1];
        tt.u4[2] = Wp[c][1][0]; tt.u4[3] = Wp[c][1][1];
        pa[u][c] = tt.s;
      }
    }
    // PV for both tiles + ones row-sums
#pragma unroll
    for (int u = 0; u < 2; ++u){
      const short* Vbuf = &Vl[(2*p + u) & 3][0];
#pragma unroll
      for (int df=0; df<4; ++df){
        int rowv = (df*16 + lr)*64;
        short8 vb0 = *(const short8*)&Vbuf[rowv + ((lg ^ vx) << 3)];
        short8 vb1 = *(const short8*)&Vbuf[rowv + (((4 + lg) ^ vx) << 3)];
        o[df] = __builtin_amdgcn_mfma_f32_16x16x32_bf16(pa[u][0], vb0, o[df], 0, 0, 0);
        o[df] = __builtin_amdgcn_mfma_f32_16x16x32_bf16(pa[u][1], vb1, o[df], 0, 0, 0);
      }
      o1 = __builtin_amdgcn_mfma_f32_16x16x32_bf16(pa[u][0], ones, o1, 0, 0, 0);
      o1 = __builtin_amdgcn_mfma_f32_16x16x32_bf16(pa[u][1], ones, o1, 0, 0, 0);
    }
    __builtin_amdgcn_s_setprio(0);
    if (p < 15){
      // pair p+1's loads were issued a full pair-compute ago -> vmcnt(0) is a near-no-op;
      // barrier frees pair p's bufs for the pair p+2 issue below.
      asm volatile("s_waitcnt vmcnt(0)" ::: "memory");
      __builtin_amdgcn_sched_barrier(0);
      __builtin_amdgcn_s_barrier();
      if (p < 14){
#pragma unroll
        for (int u = 0; u < 2; ++u){
          int t = 2*p + 4 + u, nb = t & 3;
          gload16(Kb + (size_t)t*4096 + ksrc, (char*)&Kl[nb][0] + koff);
          gload16(Vb + vsrc + t*64,           (char*)&Vl[nb][0] + koff);
        }
      }
    }
  }
  // epilogue: normalize by MFMA-computed row sums, write AO[b][s][h*64+d]
  int b = bh >> 4, hh = bh & 15;
  float rinv[4];
#pragma unroll
  for (int i2=0; i2<4; ++i2) rinv[i2] = 1.0f / o1[i2];
#pragma unroll
  for (int df=0; df<4; ++df)
#pragma unroll
    for (int i2=0; i2<4; ++i2){
      int row = q0 + lg*4 + i2;
      int col = df*16 + lr;
      AO[((size_t)(b*2048 + row))*1024 + hh*64 + col] = f2bf(o[df][i2] * rinv[i2]);
    }
}

extern "C" void kernel_launch(void* const* d_in, const int* in_sizes, int n_in,
                              void* d_out, int out_size, void* d_ws, size_t ws_size,
                              hipStream_t stream){
  const float* q  = (const float*)d_in[0];
  const float* k  = (const float*)d_in[1];
  const float* v  = (const float*)d_in[2];
  const float* Wq = (const float*)d_in[3];
  const float* bq = (const float*)d_in[4];
  const float* Wk = (const float*)d_in[5];
  const float* bk = (const float*)d_in[6];
  const float* Wv = (const float*)d_in[7];
  const float* bv = (const float*)d_in[8];
  const float* Wo = (const float*)d_in[9];
  const float* bo = (const float*)d_in[10];

  const size_t SQ = 4096ull*1024ull, NW = 1024ull*1024ull;
  short* ws  = (short*)d_ws;
  short* qb  = ws;                    // bf16 q      [4096,1024]
  short* kb  = ws + SQ;
  short* vb  = ws + 2*SQ;
  short* Wqb = ws + 3*SQ;             // bf16 weights [1024,1024]
  short* Wkb = Wqb + NW;
  short* Wvb = Wkb + NW;
  short* Wob = Wvb + NW;
  short* Qh  = Wob + NW;              // [B,H,S,D] bf16 (Q pre-scaled by log2e/8)
  short* Kh  = Qh + SQ;
  short* VhT = Kh + SQ;               // [B,H,D,S] bf16 (transposed V projection)
  short* AO  = qb;                    // reuse q buffer for attention output

  const float Csc = 0.18033688011112042f;   // log2(e)/8

  cvt_all<<<4096, 512, 0, stream>>>(q, k, v, Wq, Wk, Wv, Wo, ws);
  gemm_qkv<<<dim3(16, 48), 512, 0, stream>>>(qb, kb, vb, Wqb, Wkb, Wvb, bq, bk, bv, Qh, Kh, VhT, Csc);
  attn_fwd<<<dim3(16, 32), 512, 0, stream>>>(Qh, Kh, VhT, AO);
  gemm_out<<<dim3(16, 16), 512, 0, stream>>>(AO, Wob, bo, (float*)d_out);
}